// Round 1
// baseline (1354.800 us; speedup 1.0000x reference)
//
#include <hip/hip_runtime.h>
#include <math.h>

#define LATENT 1024
#define QDIM 256
#define NW 196608           // LATENT * CPG * K
#define BI 128
#define BC 32
#define TT 50
#define REGIONS 36
#define NGROUPS 16
#define CPG 64
#define NEG 0.1f

__device__ __forceinline__ float leakyf(float x){ return x > 0.f ? x : NEG * x; }

// ---------------------------------------------------------------------------
// Kernel 1: per-caption masked mean, gate, norm, and q = cap_repr @ red_w + b
// grid = 32 blocks, 256 threads
// ---------------------------------------------------------------------------
__global__ __launch_bounds__(256) void cap_kernel(
    const float* __restrict__ cap_embed, const int* __restrict__ lens,
    const float* __restrict__ red_w, const float* __restrict__ red_b,
    float* __restrict__ cap_repr, float* __restrict__ cap_act,
    float* __restrict__ q, float* __restrict__ norm_capr)
{
    const int n = blockIdx.x;
    const int len = lens[n];
    const float invl = 1.f / (float)len;
    __shared__ float cr[LATENT];
    for (int c = threadIdx.x; c < LATENT; c += 256) {
        float s = 0.f;
        for (int t = 0; t < len; ++t)
            s += cap_embed[((size_t)n * TT + t) * LATENT + c];
        float m = s * invl;
        cr[c] = m;
        cap_repr[n * LATENT + c] = m;
        cap_act[n * LATENT + c] = leakyf(m);
    }
    __syncthreads();
    float ss = 0.f;
    for (int c = threadIdx.x; c < LATENT; c += 256) { float v = cr[c]; ss += v * v; }
    #pragma unroll
    for (int off = 32; off; off >>= 1) ss += __shfl_xor(ss, off);
    __shared__ float red4[4];
    if ((threadIdx.x & 63) == 0) red4[threadIdx.x >> 6] = ss;
    __syncthreads();
    if (threadIdx.x == 0) norm_capr[n] = sqrtf(red4[0] + red4[1] + red4[2] + red4[3]);
    // q: one output column per thread
    const int col = threadIdx.x;
    float acc = red_b[col];
    for (int r = 0; r < LATENT; ++r)
        acc = fmaf(cr[r], red_w[r * QDIM + col], acc);
    q[n * QDIM + col] = acc;
}

// ---------------------------------------------------------------------------
// Kernel 2: Wraw[n, col] = q[n,:] dot proj_w[:, col] + proj_b[col]
// Each thread handles 2 columns for all 32 captions. grid = 384, 256 thr.
// ---------------------------------------------------------------------------
__global__ __launch_bounds__(256) void wgen_kernel(
    const float* __restrict__ q, const float* __restrict__ proj_w,
    const float* __restrict__ proj_b, float* __restrict__ Wbuf)
{
    __shared__ float qs[QDIM * BC];   // [r][n]
    for (int idx = threadIdx.x; idx < QDIM * BC; idx += 256) {
        int n = idx & 31, r = idx >> 5;
        qs[idx] = q[n * QDIM + r];
    }
    __syncthreads();
    const int col0 = blockIdx.x * 512 + threadIdx.x;
    const int col1 = col0 + 256;
    float acc0[BC], acc1[BC];
    #pragma unroll
    for (int n = 0; n < BC; ++n) { acc0[n] = 0.f; acc1[n] = 0.f; }
    for (int r = 0; r < QDIM; ++r) {
        const float w0 = proj_w[(size_t)r * NW + col0];
        const float w1 = proj_w[(size_t)r * NW + col1];
        const float* qr = &qs[r * 32];
        #pragma unroll
        for (int nb = 0; nb < 8; ++nb) {
            const float4 qv = *reinterpret_cast<const float4*>(&qr[nb * 4]);
            acc0[nb*4+0] = fmaf(w0, qv.x, acc0[nb*4+0]);
            acc0[nb*4+1] = fmaf(w0, qv.y, acc0[nb*4+1]);
            acc0[nb*4+2] = fmaf(w0, qv.z, acc0[nb*4+2]);
            acc0[nb*4+3] = fmaf(w0, qv.w, acc0[nb*4+3]);
            acc1[nb*4+0] = fmaf(w1, qv.x, acc1[nb*4+0]);
            acc1[nb*4+1] = fmaf(w1, qv.y, acc1[nb*4+1]);
            acc1[nb*4+2] = fmaf(w1, qv.z, acc1[nb*4+2]);
            acc1[nb*4+3] = fmaf(w1, qv.w, acc1[nb*4+3]);
        }
    }
    const float b0 = proj_b[col0], b1 = proj_b[col1];
    for (int n = 0; n < BC; ++n) {
        Wbuf[(size_t)n * NW + col0] = acc0[n] + b0;
        Wbuf[(size_t)n * NW + col1] = acc1[n] + b1;
    }
}

// ---------------------------------------------------------------------------
// Kernel 3: in-place softmax over K=3 on Wbuf. 2,097,152 triples.
// ---------------------------------------------------------------------------
__global__ __launch_bounds__(256) void softmax_kernel(float* __restrict__ Wbuf)
{
    const int idx = blockIdx.x * 256 + threadIdx.x;   // < 2097152
    const size_t base = (size_t)idx * 3;
    float x0 = Wbuf[base + 0], x1 = Wbuf[base + 1], x2 = Wbuf[base + 2];
    float m = fmaxf(fmaxf(x0, x1), x2);
    float e0 = expf(x0 - m), e1 = expf(x1 - m), e2 = expf(x2 - m);
    float inv = 1.f / (e0 + e1 + e2);
    Wbuf[base + 0] = e0 * inv;
    Wbuf[base + 1] = e1 * inv;
    Wbuf[base + 2] = e2 * inv;
}

// ---------------------------------------------------------------------------
// Kernel 4: grouped dynamic conv + leaky + mean(l) + gate + partial reductions
// grid = (n=32, g=16, bt=8) ; each block does 16 images in 4 chunks of 4.
// Thread tile: 4 o x 9 l for one image. 256 threads = 4 img x (16 ot x 4 lt).
// ---------------------------------------------------------------------------
__global__ __launch_bounds__(256) void conv_kernel(
    const float* __restrict__ img_embed, const float* __restrict__ Wsm,
    const float* __restrict__ cap_repr, const float* __restrict__ cap_act,
    float* __restrict__ part_dot, float* __restrict__ part_ss)
{
    const int n  = blockIdx.x;
    const int g  = blockIdx.y;
    const int bt = blockIdx.z;

    __shared__ float w_s[192 * 64];        // [r = i*3+k][o]
    __shared__ float img_s[4 * 64 * 41];   // [bsub][i][pos(41, used 0..37)]

    // stage weights: w_s[r*64+o] = Wsm[n*NW + (g*64+o)*192 + r]
    const float* Wg = Wsm + (size_t)n * NW + (size_t)g * (CPG * 192);
    for (int e = threadIdx.x; e < 192 * 64; e += 256) {
        const int o = e & 63, r = e >> 6;
        w_s[e] = Wg[o * 192 + r];
    }

    const int bsub = threadIdx.x >> 6;
    const int lane = threadIdx.x & 63;
    const int othr = lane & 15;          // 16 groups of 4 o
    const int lthr = lane >> 4;          // 4 groups of 9 l
    const int o0 = othr * 4;
    const int l0 = lthr * 9;

    const float4 ca4 = *reinterpret_cast<const float4*>(&cap_act[n * LATENT + g * CPG + o0]);
    const float4 cr4 = *reinterpret_cast<const float4*>(&cap_repr[n * LATENT + g * CPG + o0]);
    const float cav[4] = {ca4.x, ca4.y, ca4.z, ca4.w};
    const float crv[4] = {cr4.x, cr4.y, cr4.z, cr4.w};

    for (int chunk = 0; chunk < 4; ++chunk) {
        __syncthreads();   // protects w_s (chunk 0) and prev-chunk img reads
        const int b0 = bt * 16 + chunk * 4;
        // stage 4 images: img_s[bb][i][l+1] = img_embed[b, l, g*64+i]
        for (int idx = threadIdx.x; idx < 4 * REGIONS * CPG; idx += 256) {
            const int i = idx & 63;
            const int rest = idx >> 6;
            const int l = rest % REGIONS;
            const int bb = rest / REGIONS;
            img_s[bb * (64 * 41) + i * 41 + l + 1] =
                img_embed[((size_t)(b0 + bb) * REGIONS + l) * LATENT + g * CPG + i];
        }
        { // zero the two pad positions
            const int i = threadIdx.x & 63, bb = threadIdx.x >> 6;
            img_s[bb * (64 * 41) + i * 41 + 0] = 0.f;
            img_s[bb * (64 * 41) + i * 41 + 37] = 0.f;
        }
        __syncthreads();

        float acc[4][9];
        #pragma unroll
        for (int oo = 0; oo < 4; ++oo)
            #pragma unroll
            for (int j = 0; j < 9; ++j) acc[oo][j] = 0.f;

        for (int i = 0; i < CPG; ++i) {
            const float4 wa = *reinterpret_cast<const float4*>(&w_s[(i * 3 + 0) * 64 + o0]);
            const float4 wb = *reinterpret_cast<const float4*>(&w_s[(i * 3 + 1) * 64 + o0]);
            const float4 wc = *reinterpret_cast<const float4*>(&w_s[(i * 3 + 2) * 64 + o0]);
            const float* ip = &img_s[bsub * (64 * 41) + i * 41 + l0];
            float x0 = ip[0], x1 = ip[1];
            #pragma unroll
            for (int j = 0; j < 9; ++j) {
                const float x2 = ip[j + 2];
                acc[0][j] = fmaf(wa.x, x0, fmaf(wb.x, x1, fmaf(wc.x, x2, acc[0][j])));
                acc[1][j] = fmaf(wa.y, x0, fmaf(wb.y, x1, fmaf(wc.y, x2, acc[1][j])));
                acc[2][j] = fmaf(wa.z, x0, fmaf(wb.z, x1, fmaf(wc.z, x2, acc[2][j])));
                acc[3][j] = fmaf(wa.w, x0, fmaf(wb.w, x1, fmaf(wc.w, x2, acc[3][j])));
                x0 = x1; x1 = x2;
            }
        }

        // epilogue: leaky + partial l-sum, reduce over lthr (lanes +16,+32),
        // then gate and reduce over o (lanes +1,+2,+4,+8)
        float s1 = 0.f, s2 = 0.f;
        #pragma unroll
        for (int oo = 0; oo < 4; ++oo) {
            float ps = 0.f;
            #pragma unroll
            for (int j = 0; j < 9; ++j) ps += leakyf(acc[oo][j]);
            ps += __shfl_xor(ps, 16);
            ps += __shfl_xor(ps, 32);
            const float M = ps * (1.f / 36.f);
            const float tmp = M * cav[oo];
            s1 = fmaf(tmp, crv[oo], s1);
            s2 = fmaf(tmp, tmp, s2);
        }
        #pragma unroll
        for (int off = 1; off <= 8; off <<= 1) {
            s1 += __shfl_xor(s1, off);
            s2 += __shfl_xor(s2, off);
        }
        if (lane == 0) {
            const int b = b0 + bsub;
            part_dot[((size_t)n * BI + b) * NGROUPS + g] = s1;
            part_ss [((size_t)n * BI + b) * NGROUPS + g] = s2;
        }
    }
}

// ---------------------------------------------------------------------------
// Kernel 5: combine 16 group-partials -> sims[b*32+n]
// ---------------------------------------------------------------------------
__global__ __launch_bounds__(256) void final_kernel(
    const float* __restrict__ part_dot, const float* __restrict__ part_ss,
    const float* __restrict__ norm_capr, float* __restrict__ out)
{
    const int idx = blockIdx.x * 256 + threadIdx.x;   // 4096
    const int n = idx & 31;
    const int b = idx >> 5;
    const size_t base = ((size_t)n * BI + b) * NGROUPS;
    float d = 0.f, s = 0.f;
    #pragma unroll
    for (int g = 0; g < NGROUPS; ++g) { d += part_dot[base + g]; s += part_ss[base + g]; }
    out[b * BC + n] = d / (sqrtf(s) * norm_capr[n]);
}

// ---------------------------------------------------------------------------
extern "C" void kernel_launch(void* const* d_in, const int* in_sizes, int n_in,
                              void* d_out, int out_size, void* d_ws, size_t ws_size,
                              hipStream_t stream) {
    const float* img_embed = (const float*)d_in[0];   // (128, 36, 1024)
    const float* cap_embed = (const float*)d_in[1];   // (32, 50, 1024)
    const int*   lens      = (const int*)  d_in[2];   // (32,)
    const float* red_w     = (const float*)d_in[3];   // (1024, 256)
    const float* red_b     = (const float*)d_in[4];   // (256,)
    const float* proj_w    = (const float*)d_in[5];   // (256, 196608)
    const float* proj_b    = (const float*)d_in[6];   // (196608,)
    float* out = (float*)d_out;                        // (128, 32)

    char* ws = (char*)d_ws;
    float* Wbuf      = (float*)(ws);                              // 32*196608 f32 = 25165824 B
    float* cap_repr  = (float*)(ws + 25165824);                   // 131072 B
    float* cap_act   = (float*)(ws + 25165824 + 131072);          // 131072 B
    float* q         = (float*)(ws + 25165824 + 262144);          // 32768 B
    float* norm_capr = (float*)(ws + 25165824 + 294912);          // 128 B
    float* part_dot  = (float*)(ws + 25165824 + 295040);          // 262144 B
    float* part_ss   = (float*)(ws + 25165824 + 557184);          // 262144 B

    hipLaunchKernelGGL(cap_kernel, dim3(BC), dim3(256), 0, stream,
                       cap_embed, lens, red_w, red_b, cap_repr, cap_act, q, norm_capr);
    hipLaunchKernelGGL(wgen_kernel, dim3(NW / 512), dim3(256), 0, stream,
                       q, proj_w, proj_b, Wbuf);
    hipLaunchKernelGGL(softmax_kernel, dim3((BC * NW / 3) / 256), dim3(256), 0, stream,
                       Wbuf);
    hipLaunchKernelGGL(conv_kernel, dim3(BC, NGROUPS, 8), dim3(256), 0, stream,
                       img_embed, Wbuf, cap_repr, cap_act, part_dot, part_ss);
    hipLaunchKernelGGL(final_kernel, dim3(16), dim3(256), 0, stream,
                       part_dot, part_ss, norm_capr, out);
}

// Round 2
// 364.444 us; speedup vs baseline: 3.7174x; 3.7174x over previous
//
#include <hip/hip_runtime.h>
#include <math.h>

#define LATENT 1024
#define QDIM 256
#define NW 196608           // LATENT * CPG * K
#define BI 128
#define BC 32
#define TT 50
#define REGIONS 36
#define NGROUPS 16
#define CPG 64
#define NEG 0.1f

typedef __attribute__((ext_vector_type(8))) short short8;
typedef __attribute__((ext_vector_type(16))) float f32x16;

__device__ __forceinline__ float leakyf(float x){ return x > 0.f ? x : NEG * x; }

__device__ __forceinline__ unsigned short f2bf(float x){
    union { float f; unsigned int u; } v; v.f = x;
    unsigned int r = v.u + 0x7FFFu + ((v.u >> 16) & 1u);   // RNE
    return (unsigned short)(r >> 16);
}

// ---------------------------------------------------------------------------
// Kernel 1: per-caption masked mean, gate, norm, and q = cap_repr @ red_w + b
// ---------------------------------------------------------------------------
__global__ __launch_bounds__(256) void cap_kernel(
    const float* __restrict__ cap_embed, const int* __restrict__ lens,
    const float* __restrict__ red_w, const float* __restrict__ red_b,
    float* __restrict__ cap_repr, float* __restrict__ cap_act,
    float* __restrict__ q, float* __restrict__ norm_capr)
{
    const int n = blockIdx.x;
    const int len = lens[n];
    const float invl = 1.f / (float)len;
    __shared__ float cr[LATENT];
    for (int c = threadIdx.x; c < LATENT; c += 256) {
        float s = 0.f;
        for (int t = 0; t < len; ++t)
            s += cap_embed[((size_t)n * TT + t) * LATENT + c];
        float m = s * invl;
        cr[c] = m;
        cap_repr[n * LATENT + c] = m;
        cap_act[n * LATENT + c] = leakyf(m);
    }
    __syncthreads();
    float ss = 0.f;
    for (int c = threadIdx.x; c < LATENT; c += 256) { float v = cr[c]; ss += v * v; }
    #pragma unroll
    for (int off = 32; off; off >>= 1) ss += __shfl_xor(ss, off);
    __shared__ float red4[4];
    if ((threadIdx.x & 63) == 0) red4[threadIdx.x >> 6] = ss;
    __syncthreads();
    if (threadIdx.x == 0) norm_capr[n] = sqrtf(red4[0] + red4[1] + red4[2] + red4[3]);
    const int col = threadIdx.x;
    float acc = red_b[col];
    for (int r = 0; r < LATENT; ++r)
        acc = fmaf(cr[r], red_w[r * QDIM + col], acc);
    q[n * QDIM + col] = acc;
}

// ---------------------------------------------------------------------------
// Kernel 2: wgen2 — per col-triple GEMM + bias + softmax(K=3) + bf16 pack,
// output layout Wp2[n][g][k][o][i]  (4096 bf16 per (n,g,k))
// grid = 256 blocks x 256 thr; thread owns triple c = (g,o,i) for all 32 n.
// ---------------------------------------------------------------------------
__global__ __launch_bounds__(256) void wgen2_kernel(
    const float* __restrict__ q, const float* __restrict__ proj_w,
    const float* __restrict__ proj_b, unsigned short* __restrict__ Wp2)
{
    __shared__ float qs[QDIM * BC];   // [r][n]
    for (int idx = threadIdx.x; idx < QDIM * BC; idx += 256) {
        int n = idx & 31, r = idx >> 5;
        qs[idx] = q[n * QDIM + r];
    }
    __syncthreads();
    const int c = blockIdx.x * 256 + threadIdx.x;   // triple index, < 65536
    const size_t col = (size_t)c * 3;
    float a0[BC], a1[BC], a2[BC];
    #pragma unroll
    for (int n = 0; n < BC; ++n) { a0[n] = 0.f; a1[n] = 0.f; a2[n] = 0.f; }
    for (int r = 0; r < QDIM; ++r) {
        const float w0 = proj_w[(size_t)r * NW + col];
        const float w1 = proj_w[(size_t)r * NW + col + 1];
        const float w2 = proj_w[(size_t)r * NW + col + 2];
        const float* qr = &qs[r * 32];
        #pragma unroll
        for (int nb = 0; nb < 8; ++nb) {
            const float4 qv = *reinterpret_cast<const float4*>(&qr[nb * 4]);
            a0[nb*4+0] = fmaf(w0, qv.x, a0[nb*4+0]);
            a0[nb*4+1] = fmaf(w0, qv.y, a0[nb*4+1]);
            a0[nb*4+2] = fmaf(w0, qv.z, a0[nb*4+2]);
            a0[nb*4+3] = fmaf(w0, qv.w, a0[nb*4+3]);
            a1[nb*4+0] = fmaf(w1, qv.x, a1[nb*4+0]);
            a1[nb*4+1] = fmaf(w1, qv.y, a1[nb*4+1]);
            a1[nb*4+2] = fmaf(w1, qv.z, a1[nb*4+2]);
            a1[nb*4+3] = fmaf(w1, qv.w, a1[nb*4+3]);
            a2[nb*4+0] = fmaf(w2, qv.x, a2[nb*4+0]);
            a2[nb*4+1] = fmaf(w2, qv.y, a2[nb*4+1]);
            a2[nb*4+2] = fmaf(w2, qv.z, a2[nb*4+2]);
            a2[nb*4+3] = fmaf(w2, qv.w, a2[nb*4+3]);
        }
    }
    const float b0 = proj_b[col], b1 = proj_b[col + 1], b2 = proj_b[col + 2];
    const int g = c >> 12, o = (c >> 6) & 63, i = c & 63;
    #pragma unroll
    for (int n = 0; n < BC; ++n) {
        float x0 = a0[n] + b0, x1 = a1[n] + b1, x2 = a2[n] + b2;
        float m = fmaxf(fmaxf(x0, x1), x2);
        float e0 = expf(x0 - m), e1 = expf(x1 - m), e2 = expf(x2 - m);
        float inv = 1.f / (e0 + e1 + e2);
        size_t ob = ((size_t)((n * 16 + g) * 3)) * 4096 + o * 64 + i;
        Wp2[ob]        = f2bf(e0 * inv);
        Wp2[ob + 4096] = f2bf(e1 * inv);
        Wp2[ob + 8192] = f2bf(e2 * inv);
    }
}

// ---------------------------------------------------------------------------
// Kernel 3: img f32 -> bf16 (same layout)
// ---------------------------------------------------------------------------
__global__ __launch_bounds__(256) void img2bf_kernel(
    const float* __restrict__ in, unsigned short* __restrict__ out)
{
    const size_t base = ((size_t)blockIdx.x * 256 + threadIdx.x) * 8;
    const float4 u = *reinterpret_cast<const float4*>(in + base);
    const float4 v = *reinterpret_cast<const float4*>(in + base + 4);
    unsigned short r[8];
    r[0]=f2bf(u.x); r[1]=f2bf(u.y); r[2]=f2bf(u.z); r[3]=f2bf(u.w);
    r[4]=f2bf(v.x); r[5]=f2bf(v.y); r[6]=f2bf(v.z); r[7]=f2bf(v.w);
    *reinterpret_cast<int4*>(out + base) = *reinterpret_cast<const int4*>(r);
}

// ---------------------------------------------------------------------------
// Kernel 4: MFMA grouped conv + leaky + mean + gate + partial reductions
// grid=(n=32, g=16, bchunk=16 of 8 images), 192 thr = 3 waves.
// Wave w: rows [w*96, w*96+96) (3 M-tiles of 32), all 64 o (2 N-tiles).
// GEMM-per-tap: C[l] += A[l+k] * B_k  with per-image zero-pad rows in LDS.
// ---------------------------------------------------------------------------
__global__ __launch_bounds__(192) void conv_mfma_kernel(
    const unsigned short* __restrict__ img_bf, const unsigned short* __restrict__ Wp2,
    const float* __restrict__ cap_repr, const float* __restrict__ cap_act,
    float* __restrict__ part_dot, float* __restrict__ part_ss)
{
    const int n = blockIdx.x, g = blockIdx.y, bz = blockIdx.z;
    const int b0 = bz * 8;
    __shared__ char Asm[8 * 38 * 128];   // [row=b*38+pos][64 bf16], swizzled
    __shared__ char Bsm[192 * 128];      // [row=k*64+o][64 bf16], swizzled
    __shared__ float S[8][64];
    const int tid = threadIdx.x;

    for (int idx = tid; idx < 512; idx += 192) ((float*)S)[idx] = 0.f;

    // stage A: 8 imgs x 36 rows x 8 chunks of 16B
    const unsigned short* imgG = img_bf + (size_t)b0 * 36 * 1024 + g * 64;
    for (int idx = tid; idx < 2304; idx += 192) {
        const int row_img = idx >> 3, ch = idx & 7;
        const int bb = row_img / 36;
        const int l = row_img - bb * 36;
        const int4 v = *reinterpret_cast<const int4*>(imgG + (size_t)row_img * 1024 + ch * 8);
        const int arow = bb * 38 + l + 1;
        const int byte = (arow * 128 + ch * 16) ^ ((arow & 7) << 4);
        *reinterpret_cast<int4*>(Asm + byte) = v;
    }
    // zero pad rows (pos 0 and 37 per image): 16 rows x 8 chunks
    for (int idx = tid; idx < 128; idx += 192) {
        const int r = idx >> 3, ch = idx & 7;
        const int arow = (r >> 1) * 38 + (r & 1) * 37;
        const int byte = (arow * 128 + ch * 16) ^ ((arow & 7) << 4);
        *reinterpret_cast<int4*>(Bsm + 0) = *reinterpret_cast<int4*>(Bsm + 0); // no-op placeholder removed below
        int4 z; z.x = 0; z.y = 0; z.z = 0; z.w = 0;
        *reinterpret_cast<int4*>(Asm + byte) = z;
    }
    // stage B: Wp2 region for (n,g): 3*4096 bf16 = 1536 chunks of 16B
    const unsigned short* WG = Wp2 + (size_t)(n * 16 + g) * 3 * 4096;
    for (int idx = tid; idx < 1536; idx += 192) {
        const int4 v = *reinterpret_cast<const int4*>(WG + idx * 8);
        const int brow = idx >> 3;           // k*64 + o
        const int byte = (idx * 16) ^ ((brow & 7) << 4);
        *reinterpret_cast<int4*>(Bsm + byte) = v;
    }
    __syncthreads();

    const int wv = tid >> 6, lane = tid & 63;
    const int lrow = lane & 31, khalf = lane >> 5;
    const int ioff = khalf * 16;             // byte offset of the 8-elem k-half

    int abase[3];
    #pragma unroll
    for (int mt = 0; mt < 3; ++mt) {
        const int r = wv * 96 + mt * 32 + lrow;
        const int bb = r / 36;
        abase[mt] = bb * 38 + (r - bb * 36);
    }

    f32x16 acc[3][2] = {};
    #pragma unroll
    for (int k = 0; k < 3; ++k) {
        #pragma unroll
        for (int ks = 0; ks < 4; ++ks) {
            short8 bfrag[2];
            #pragma unroll
            for (int nt = 0; nt < 2; ++nt) {
                const int brow = k * 64 + nt * 32 + lrow;
                const int byte = (brow * 128 + ks * 32 + ioff) ^ ((brow & 7) << 4);
                bfrag[nt] = *reinterpret_cast<const short8*>(Bsm + byte);
            }
            #pragma unroll
            for (int mt = 0; mt < 3; ++mt) {
                const int arow = abase[mt] + k;
                const int byte = (arow * 128 + ks * 32 + ioff) ^ ((arow & 7) << 4);
                const short8 afrag = *reinterpret_cast<const short8*>(Asm + byte);
                acc[mt][0] = __builtin_amdgcn_mfma_f32_32x32x16_bf16(afrag, bfrag[0], acc[mt][0], 0, 0, 0);
                acc[mt][1] = __builtin_amdgcn_mfma_f32_32x32x16_bf16(afrag, bfrag[1], acc[mt][1], 0, 0, 0);
            }
        }
    }

    // epilogue: leaky + per-(b,o) l-sums into S via LDS atomics
    // C/D layout (m74/m101): col=lane&31, row_in_tile=(reg&3)+8*(reg>>2)+4*(lane>>5)
    #pragma unroll
    for (int mt = 0; mt < 3; ++mt) {
        const int rbase = wv * 96 + mt * 32;
        const int bfirst = rbase / 36;
        const int bsplit = (bfirst + 1) * 36 - rbase;   // rows >= bsplit belong to bfirst+1
        #pragma unroll
        for (int nt = 0; nt < 2; ++nt) {
            float sA = 0.f, sB = 0.f;
            #pragma unroll
            for (int reg = 0; reg < 16; ++reg) {
                const int rit = (reg & 3) + 8 * (reg >> 2) + 4 * khalf;
                const float v = leakyf(acc[mt][nt][reg]);
                if (rit >= bsplit) sB += v; else sA += v;
            }
            const int o = nt * 32 + lrow;
            atomicAdd(&S[bfirst][o], sA);
            if (bsplit < 32) atomicAdd(&S[bfirst + 1][o], sB);
        }
    }
    __syncthreads();

    // final: S[b][o] -> gated partial dot/ss per b
    if (tid < 128) {
        const int b = tid >> 4, j = tid & 15;
        float d = 0.f, ss = 0.f;
        #pragma unroll
        for (int u = 0; u < 4; ++u) {
            const int o = j * 4 + u;
            const float M = S[b][o] * (1.f / 36.f);
            const float ca = cap_act[n * LATENT + g * CPG + o];
            const float crv = cap_repr[n * LATENT + g * CPG + o];
            const float tmp = M * ca;
            d = fmaf(tmp, crv, d);
            ss = fmaf(tmp, tmp, ss);
        }
        #pragma unroll
        for (int off = 1; off <= 8; off <<= 1) {
            d += __shfl_xor(d, off);
            ss += __shfl_xor(ss, off);
        }
        if (j == 0) {
            part_dot[((size_t)n * BI + b0 + b) * NGROUPS + g] = d;
            part_ss [((size_t)n * BI + b0 + b) * NGROUPS + g] = ss;
        }
    }
}

// ---------------------------------------------------------------------------
// Kernel 5: combine 16 group-partials -> sims[b*32+n]
// ---------------------------------------------------------------------------
__global__ __launch_bounds__(256) void final_kernel(
    const float* __restrict__ part_dot, const float* __restrict__ part_ss,
    const float* __restrict__ norm_capr, float* __restrict__ out)
{
    const int idx = blockIdx.x * 256 + threadIdx.x;   // 4096
    const int n = idx & 31;
    const int b = idx >> 5;
    const size_t base = ((size_t)n * BI + b) * NGROUPS;
    float d = 0.f, s = 0.f;
    #pragma unroll
    for (int g = 0; g < NGROUPS; ++g) { d += part_dot[base + g]; s += part_ss[base + g]; }
    out[b * BC + n] = d / (sqrtf(s) * norm_capr[n]);
}

// ---------------------------------------------------------------------------
extern "C" void kernel_launch(void* const* d_in, const int* in_sizes, int n_in,
                              void* d_out, int out_size, void* d_ws, size_t ws_size,
                              hipStream_t stream) {
    const float* img_embed = (const float*)d_in[0];   // (128, 36, 1024)
    const float* cap_embed = (const float*)d_in[1];   // (32, 50, 1024)
    const int*   lens      = (const int*)  d_in[2];   // (32,)
    const float* red_w     = (const float*)d_in[3];   // (1024, 256)
    const float* red_b     = (const float*)d_in[4];   // (256,)
    const float* proj_w    = (const float*)d_in[5];   // (256, 196608)
    const float* proj_b    = (const float*)d_in[6];   // (196608,)
    float* out = (float*)d_out;                        // (128, 32)

    char* ws = (char*)d_ws;
    unsigned short* Wp2    = (unsigned short*)(ws);                    // 12,582,912 B
    unsigned short* img_bf = (unsigned short*)(ws + 12582912);         //  9,437,184 B
    float* cap_repr  = (float*)(ws + 22020096);                        //    131,072 B
    float* cap_act   = (float*)(ws + 22151168);                        //    131,072 B
    float* q         = (float*)(ws + 22282240);                        //     32,768 B
    float* norm_capr = (float*)(ws + 22315008);                        //        512 B
    float* part_dot  = (float*)(ws + 22315520);                        //    262,144 B
    float* part_ss   = (float*)(ws + 22577664);                        //    262,144 B

    hipLaunchKernelGGL(cap_kernel, dim3(BC), dim3(256), 0, stream,
                       cap_embed, lens, red_w, red_b, cap_repr, cap_act, q, norm_capr);
    hipLaunchKernelGGL(img2bf_kernel, dim3(2304), dim3(256), 0, stream,
                       img_embed, img_bf);
    hipLaunchKernelGGL(wgen2_kernel, dim3(256), dim3(256), 0, stream,
                       q, proj_w, proj_b, Wp2);
    hipLaunchKernelGGL(conv_mfma_kernel, dim3(BC, NGROUPS, 16), dim3(192), 0, stream,
                       img_bf, Wp2, cap_repr, cap_act, part_dot, part_ss);
    hipLaunchKernelGGL(final_kernel, dim3(16), dim3(256), 0, stream,
                       part_dot, part_ss, norm_capr, out);
}

// Round 3
// 293.212 us; speedup vs baseline: 4.6205x; 1.2429x over previous
//
#include <hip/hip_runtime.h>
#include <math.h>

#define LATENT 1024
#define QDIM 256
#define NW 196608           // LATENT * CPG * K
#define BI 128
#define BC 32
#define TT 50
#define REGIONS 36
#define NGROUPS 16
#define CPG 64
#define NEG 0.1f

typedef __attribute__((ext_vector_type(8))) short short8;
typedef __attribute__((ext_vector_type(16))) float f32x16;

__device__ __forceinline__ float leakyf(float x){ return x > 0.f ? x : NEG * x; }

__device__ __forceinline__ unsigned short f2bf(float x){
    union { float f; unsigned int u; } v; v.f = x;
    unsigned int r = v.u + 0x7FFFu + ((v.u >> 16) & 1u);   // RNE
    return (unsigned short)(r >> 16);
}

// ---------------------------------------------------------------------------
// Kernel 1a: masked mean over words + gate + ||cap_repr||. grid=32, 256 thr.
// ---------------------------------------------------------------------------
__global__ __launch_bounds__(256) void cap_mean_kernel(
    const float* __restrict__ cap_embed, const int* __restrict__ lens,
    float* __restrict__ cap_repr, float* __restrict__ cap_act,
    float* __restrict__ norm_capr)
{
    const int n = blockIdx.x;
    const int len = lens[n];
    const float invl = 1.f / (float)len;
    const int c4 = threadIdx.x;            // 4 channels per thread
    const float* base = cap_embed + (size_t)n * TT * LATENT + c4 * 4;
    float4 s = {0.f, 0.f, 0.f, 0.f};
    for (int t = 0; t < len; ++t) {
        const float4 v = *reinterpret_cast<const float4*>(base + (size_t)t * LATENT);
        s.x += v.x; s.y += v.y; s.z += v.z; s.w += v.w;
    }
    float4 m = {s.x * invl, s.y * invl, s.z * invl, s.w * invl};
    *reinterpret_cast<float4*>(cap_repr + n * LATENT + c4 * 4) = m;
    float4 a = {leakyf(m.x), leakyf(m.y), leakyf(m.z), leakyf(m.w)};
    *reinterpret_cast<float4*>(cap_act + n * LATENT + c4 * 4) = a;
    float ss = m.x*m.x + m.y*m.y + m.z*m.z + m.w*m.w;
    #pragma unroll
    for (int off = 32; off; off >>= 1) ss += __shfl_xor(ss, off);
    __shared__ float red4[4];
    if ((threadIdx.x & 63) == 0) red4[threadIdx.x >> 6] = ss;
    __syncthreads();
    if (threadIdx.x == 0) norm_capr[n] = sqrtf(red4[0] + red4[1] + red4[2] + red4[3]);
}

// ---------------------------------------------------------------------------
// Kernel 1b: qT[col][n] = cap_repr[n,:] @ red_w[:,col] + red_b[col]
// grid=(8 colgroups, 32 n), 256 thr = 32 cols x 8 K-slices.
// ---------------------------------------------------------------------------
__global__ __launch_bounds__(256) void q_kernel(
    const float* __restrict__ cap_repr, const float* __restrict__ red_w,
    const float* __restrict__ red_b, float* __restrict__ qT)
{
    const int cg = blockIdx.x, n = blockIdx.y;
    const int col = threadIdx.x & 31, ks = threadIdx.x >> 5;
    const float* cr = cap_repr + n * LATENT;
    float p = 0.f;
    const int r0 = ks * 128;
    for (int r = r0; r < r0 + 128; ++r)
        p = fmaf(cr[r], red_w[(size_t)r * QDIM + cg * 32 + col], p);
    __shared__ float part[256];
    part[threadIdx.x] = p;
    __syncthreads();
    if (threadIdx.x < 32) {
        float s = red_b[cg * 32 + col];
        #pragma unroll
        for (int k = 0; k < 8; ++k) s += part[k * 32 + col];
        qT[(cg * 32 + col) * 32 + n] = s;
    }
}

// ---------------------------------------------------------------------------
// Kernel 2: img f32 -> bf16 (same layout)
// ---------------------------------------------------------------------------
__global__ __launch_bounds__(256) void img2bf_kernel(
    const float* __restrict__ in, unsigned short* __restrict__ out)
{
    const size_t base = ((size_t)blockIdx.x * 256 + threadIdx.x) * 8;
    const float4 u = *reinterpret_cast<const float4*>(in + base);
    const float4 v = *reinterpret_cast<const float4*>(in + base + 4);
    unsigned short r[8];
    r[0]=f2bf(u.x); r[1]=f2bf(u.y); r[2]=f2bf(u.z); r[3]=f2bf(u.w);
    r[4]=f2bf(v.x); r[5]=f2bf(v.y); r[6]=f2bf(v.z); r[7]=f2bf(v.w);
    *reinterpret_cast<int4*>(out + base) = *reinterpret_cast<const int4*>(r);
}

// ---------------------------------------------------------------------------
// Kernel 3: wgen3 — thread = one proj column for all 32 captions.
// grid = 512 x 384 thr (196608 cols). LDS: qs[256][32] then logits[384][33].
// Epilogue: softmax over col-triples + bf16 pack to Wp2[n][g][k][o][i].
// ---------------------------------------------------------------------------
__global__ __launch_bounds__(384) void wgen3_kernel(
    const float* __restrict__ qT, const float* __restrict__ proj_w,
    const float* __restrict__ proj_b, unsigned short* __restrict__ Wp2)
{
    __shared__ float smem[384 * 33];      // 50688 B
    float* qs = smem;                     // first 8192 floats: [r][n]
    for (int idx = threadIdx.x; idx < QDIM * BC; idx += 384) qs[idx] = qT[idx];
    __syncthreads();

    const int col = blockIdx.x * 384 + threadIdx.x;
    float acc[32];
    #pragma unroll
    for (int n = 0; n < 32; ++n) acc[n] = 0.f;
    const float* pw = proj_w + col;
    #pragma unroll 4
    for (int r = 0; r < QDIM; ++r) {
        const float w = pw[(size_t)r * NW];
        const float* qr = qs + r * 32;
        #pragma unroll
        for (int nb = 0; nb < 8; ++nb) {
            const float4 qv = *reinterpret_cast<const float4*>(qr + nb * 4);
            acc[nb*4+0] = fmaf(w, qv.x, acc[nb*4+0]);
            acc[nb*4+1] = fmaf(w, qv.y, acc[nb*4+1]);
            acc[nb*4+2] = fmaf(w, qv.z, acc[nb*4+2]);
            acc[nb*4+3] = fmaf(w, qv.w, acc[nb*4+3]);
        }
    }
    const float b = proj_b[col];
    __syncthreads();                      // all threads done reading qs
    float* L = smem;                      // [col_in_block][n], stride 33
    #pragma unroll
    for (int n = 0; n < 32; ++n) L[threadIdx.x * 33 + n] = acc[n] + b;
    __syncthreads();

    const int g = blockIdx.x >> 5;               // 32 blocks per group
    const int locbase = (blockIdx.x & 31) * 128; // o*64+i base of this block
    for (int idx = threadIdx.x; idx < 4096; idx += 384) {
        const int n = idx >> 7, tl = idx & 127;
        const int c = tl * 3;
        const float x0 = L[c * 33 + n];
        const float x1 = L[(c + 1) * 33 + n];
        const float x2 = L[(c + 2) * 33 + n];
        const float m = fmaxf(fmaxf(x0, x1), x2);
        const float e0 = expf(x0 - m), e1 = expf(x1 - m), e2 = expf(x2 - m);
        const float inv = 1.f / (e0 + e1 + e2);
        const size_t ob = ((size_t)(n * 16 + g) * 3) * 4096 + locbase + tl;
        Wp2[ob]        = f2bf(e0 * inv);
        Wp2[ob + 4096] = f2bf(e1 * inv);
        Wp2[ob + 8192] = f2bf(e2 * inv);
    }
}

// ---------------------------------------------------------------------------
// Kernel 4: MFMA grouped conv; block=(g, bchunk of 8 imgs, n-quarter),
// loops 8 captions reusing the staged A tile. 192 thr = 3 waves.
// ---------------------------------------------------------------------------
__global__ __launch_bounds__(192) void conv2_kernel(
    const unsigned short* __restrict__ img_bf, const unsigned short* __restrict__ Wp2,
    const float* __restrict__ cap_repr, const float* __restrict__ cap_act,
    float* __restrict__ part_dot, float* __restrict__ part_ss)
{
    const int g = blockIdx.x, bt = blockIdx.y, nq = blockIdx.z;
    const int b0 = bt * 8;
    __shared__ char Asm[8 * 38 * 128];   // [row=b*38+pos][64 bf16], swizzled
    __shared__ char Bsm[192 * 128];      // [row=k*64+o][64 bf16], swizzled
    __shared__ float S[8][64];
    const int tid = threadIdx.x;

    // stage A once per block (reused for 8 captions)
    const unsigned short* imgG = img_bf + (size_t)b0 * 36 * 1024 + g * 64;
    for (int idx = tid; idx < 2304; idx += 192) {
        const int row_img = idx >> 3, ch = idx & 7;
        const int bb = row_img / 36;
        const int l = row_img - bb * 36;
        const int4 v = *reinterpret_cast<const int4*>(imgG + (size_t)row_img * 1024 + ch * 8);
        const int arow = bb * 38 + l + 1;
        const int byte = (arow * 128 + ch * 16) ^ ((arow & 7) << 4);
        *reinterpret_cast<int4*>(Asm + byte) = v;
    }
    for (int idx = tid; idx < 128; idx += 192) {   // zero pad rows
        const int r = idx >> 3, ch = idx & 7;
        const int arow = (r >> 1) * 38 + (r & 1) * 37;
        const int byte = (arow * 128 + ch * 16) ^ ((arow & 7) << 4);
        int4 z; z.x = 0; z.y = 0; z.z = 0; z.w = 0;
        *reinterpret_cast<int4*>(Asm + byte) = z;
    }

    const int wv = tid >> 6, lane = tid & 63;
    const int lrow = lane & 31, khalf = lane >> 5;
    const int ioff = khalf * 16;
    int abase[3];
    #pragma unroll
    for (int mt = 0; mt < 3; ++mt) {
        const int r = wv * 96 + mt * 32 + lrow;
        const int bb = r / 36;
        abase[mt] = bb * 38 + (r - bb * 36);
    }

    for (int ni = 0; ni < 8; ++ni) {
        const int n = nq * 8 + ni;
        __syncthreads();   // A ready (first iter); prev S reads / B reads done

        for (int idx = tid; idx < 512; idx += 192) ((float*)S)[idx] = 0.f;
        const unsigned short* WG = Wp2 + (size_t)(n * 16 + g) * 3 * 4096;
        for (int idx = tid; idx < 1536; idx += 192) {
            const int4 v = *reinterpret_cast<const int4*>(WG + idx * 8);
            const int brow = idx >> 3;           // k*64 + o
            const int byte = (idx * 16) ^ ((brow & 7) << 4);
            *reinterpret_cast<int4*>(Bsm + byte) = v;
        }
        __syncthreads();

        f32x16 acc[3][2] = {};
        #pragma unroll
        for (int k = 0; k < 3; ++k) {
            #pragma unroll
            for (int ks = 0; ks < 4; ++ks) {
                short8 bfrag[2];
                #pragma unroll
                for (int nt = 0; nt < 2; ++nt) {
                    const int brow = k * 64 + nt * 32 + lrow;
                    const int byte = (brow * 128 + ks * 32 + ioff) ^ ((brow & 7) << 4);
                    bfrag[nt] = *reinterpret_cast<const short8*>(Bsm + byte);
                }
                #pragma unroll
                for (int mt = 0; mt < 3; ++mt) {
                    const int arow = abase[mt] + k;
                    const int byte = (arow * 128 + ks * 32 + ioff) ^ ((arow & 7) << 4);
                    const short8 afrag = *reinterpret_cast<const short8*>(Asm + byte);
                    acc[mt][0] = __builtin_amdgcn_mfma_f32_32x32x16_bf16(afrag, bfrag[0], acc[mt][0], 0, 0, 0);
                    acc[mt][1] = __builtin_amdgcn_mfma_f32_32x32x16_bf16(afrag, bfrag[1], acc[mt][1], 0, 0, 0);
                }
            }
        }

        // leaky + per-(b,o) l-sums into S (C/D: col=lane&31, row=(reg&3)+8*(reg>>2)+4*khalf)
        #pragma unroll
        for (int mt = 0; mt < 3; ++mt) {
            const int rbase = wv * 96 + mt * 32;
            const int bfirst = rbase / 36;
            const int bsplit = (bfirst + 1) * 36 - rbase;
            #pragma unroll
            for (int nt = 0; nt < 2; ++nt) {
                float sA = 0.f, sB = 0.f;
                #pragma unroll
                for (int reg = 0; reg < 16; ++reg) {
                    const int rit = (reg & 3) + 8 * (reg >> 2) + 4 * khalf;
                    const float v = leakyf(acc[mt][nt][reg]);
                    if (rit >= bsplit) sB += v; else sA += v;
                }
                const int o = nt * 32 + lrow;
                atomicAdd(&S[bfirst][o], sA);
                if (bsplit < 32) atomicAdd(&S[bfirst + 1][o], sB);
            }
        }
        __syncthreads();

        if (tid < 128) {
            const int b = tid >> 4, j = tid & 15;
            float d = 0.f, ss = 0.f;
            #pragma unroll
            for (int u = 0; u < 4; ++u) {
                const int o = j * 4 + u;
                const float M = S[b][o] * (1.f / 36.f);
                const float ca = cap_act[n * LATENT + g * CPG + o];
                const float crv = cap_repr[n * LATENT + g * CPG + o];
                const float tmp = M * ca;
                d = fmaf(tmp, crv, d);
                ss = fmaf(tmp, tmp, ss);
            }
            #pragma unroll
            for (int off = 1; off <= 8; off <<= 1) {
                d += __shfl_xor(d, off);
                ss += __shfl_xor(ss, off);
            }
            if (j == 0) {
                part_dot[((size_t)n * BI + b0 + b) * NGROUPS + g] = d;
                part_ss [((size_t)n * BI + b0 + b) * NGROUPS + g] = ss;
            }
        }
    }
}

// ---------------------------------------------------------------------------
// Kernel 5: combine 16 group-partials -> sims[b*32+n]
// ---------------------------------------------------------------------------
__global__ __launch_bounds__(256) void final_kernel(
    const float* __restrict__ part_dot, const float* __restrict__ part_ss,
    const float* __restrict__ norm_capr, float* __restrict__ out)
{
    const int idx = blockIdx.x * 256 + threadIdx.x;   // 4096
    const int n = idx & 31;
    const int b = idx >> 5;
    const size_t base = ((size_t)n * BI + b) * NGROUPS;
    float d = 0.f, s = 0.f;
    #pragma unroll
    for (int g = 0; g < NGROUPS; ++g) { d += part_dot[base + g]; s += part_ss[base + g]; }
    out[b * BC + n] = d / (sqrtf(s) * norm_capr[n]);
}

// ---------------------------------------------------------------------------
extern "C" void kernel_launch(void* const* d_in, const int* in_sizes, int n_in,
                              void* d_out, int out_size, void* d_ws, size_t ws_size,
                              hipStream_t stream) {
    const float* img_embed = (const float*)d_in[0];   // (128, 36, 1024)
    const float* cap_embed = (const float*)d_in[1];   // (32, 50, 1024)
    const int*   lens      = (const int*)  d_in[2];   // (32,)
    const float* red_w     = (const float*)d_in[3];   // (1024, 256)
    const float* red_b     = (const float*)d_in[4];   // (256,)
    const float* proj_w    = (const float*)d_in[5];   // (256, 196608)
    const float* proj_b    = (const float*)d_in[6];   // (196608,)
    float* out = (float*)d_out;                        // (128, 32)

    char* ws = (char*)d_ws;
    unsigned short* Wp2    = (unsigned short*)(ws);                    // 12,582,912 B
    unsigned short* img_bf = (unsigned short*)(ws + 12582912);         //  9,437,184 B
    float* cap_repr  = (float*)(ws + 22020096);                        //    131,072 B
    float* cap_act   = (float*)(ws + 22151168);                        //    131,072 B
    float* qT        = (float*)(ws + 22282240);                        //     32,768 B
    float* norm_capr = (float*)(ws + 22315008);                        //        512 B
    float* part_dot  = (float*)(ws + 22315520);                        //    262,144 B
    float* part_ss   = (float*)(ws + 22577664);                        //    262,144 B

    hipLaunchKernelGGL(cap_mean_kernel, dim3(BC), dim3(256), 0, stream,
                       cap_embed, lens, cap_repr, cap_act, norm_capr);
    hipLaunchKernelGGL(q_kernel, dim3(8, BC), dim3(256), 0, stream,
                       cap_repr, red_w, red_b, qT);
    hipLaunchKernelGGL(img2bf_kernel, dim3(2304), dim3(256), 0, stream,
                       img_embed, img_bf);
    hipLaunchKernelGGL(wgen3_kernel, dim3(512), dim3(384), 0, stream,
                       qT, proj_w, proj_b, Wp2);
    hipLaunchKernelGGL(conv2_kernel, dim3(NGROUPS, 16, 4), dim3(192), 0, stream,
                       img_bf, Wp2, cap_repr, cap_act, part_dot, part_ss);
    hipLaunchKernelGGL(final_kernel, dim3(16), dim3(256), 0, stream,
                       part_dot, part_ss, norm_capr, out);
}